// Round 8
// baseline (189.330 us; speedup 1.0000x reference)
//
#include <hip/hip_runtime.h>
#include <hip/hip_fp16.h>
#include <math.h>

#define H_   4
#define HD_  32
#define B_   16
#define M_   128
#define N_   256
#define MC_  16                      /* m-chunks (partials) */
#define MCH_ 8                       /* m's per chunk */
#define SCALE_ 0.17677669529663687f  /* 1/sqrt(32) */

__device__ __forceinline__ float lrelu_f(float x) { return x >= 0.f ? x : 0.2f * x; }

__device__ __forceinline__ __half2 u2h_(unsigned u) {
  union { unsigned u; __half2 h; } c; c.u = u; return c.h;
}
__device__ __forceinline__ __half2 habs2_(__half2 x) {
  union { __half2 h; unsigned u; } c; c.h = x; c.u &= 0x7FFF7FFFu; return c.h;
}
__device__ __forceinline__ unsigned splat2_(float f) {
  unsigned short s = __half_as_ushort(__float2half(f));
  return (unsigned)s | ((unsigned)s << 16);
}

// ---------------- K2: proj(U,A)+LN fused + packed-f16 scores -> softmax -> partials ----
// block = (h, b, mc) = 1024 blocks; thread = n. Per-d LDS row (32B): 8 U f16 (m-pairs) +
// splat (c,c)(b,b)(.6v,.6v)(.4v,.4v). Score/PV in v_pk half2 math, f32 flush every 8 d.
__global__ __launch_bounds__(256) void k2_attn(
    const float* __restrict__ uf, const float* __restrict__ af,
    const float* __restrict__ edge,
    const float* __restrict__ Wu, const float* __restrict__ gu, const float* __restrict__ bu,
    const float* __restrict__ Wa, const float* __restrict__ ga, const float* __restrict__ ba,
    const float* __restrict__ We, const float* __restrict__ ge, const float* __restrict__ be,
    const float* __restrict__ av, unsigned short* __restrict__ P)
{
  int blk = blockIdx.x;
  int h = blk & 3, b = (blk >> 2) & 15, mc = blk >> 6;   // mc in 0..15
  int tid = threadIdx.x, n = tid;
  int lane = tid & 63, wid = tid >> 6;
  __shared__ __align__(16) unsigned short As[HD_ * N_];   // A f16 transposed [d][n], 16 KB
  __shared__ __align__(16) unsigned short accs[N_ * 34];  // acc f16 [n][34-pad], 17.4 KB
  __shared__ __align__(16) unsigned short rows[HD_ * 16]; // per-d 32B row, 1 KB
  __shared__ float wred[2][MCH_][4];
  __shared__ float vw_s;

  if (tid < 32) {                         // per-head edge-LN constants -> rows[d][8..15]
    int d = tid;
    float w = We[h * HD_ + d];
    float s = w;
    #pragma unroll
    for (int o = 16; o > 0; o >>= 1) s += __shfl_xor(s, o, 32);
    float mw = s * (1.f / 32.f);
    float df = w - mw;
    float v2 = df * df;
    #pragma unroll
    for (int o = 16; o > 0; o >>= 1) v2 += __shfl_xor(v2, o, 32);
    if (d == 0) vw_s = v2 * (1.f / 32.f);
    float vvf = av[h * HD_ + d] * SCALE_;
    uint4 t;
    t.x = splat2_(df * ge[h * HD_ + d]);
    t.y = splat2_(be[h * HD_ + d]);
    t.z = splat2_(0.6f * vvf);
    t.w = splat2_(0.4f * vvf);
    *(uint4*)&rows[d * 16 + 8] = t;
  }
  int m0 = mc * MCH_;
  if (tid < 128) {  // U projection + LN + leaky -> rows[d][m_loc] f16. 16 thr/row, 2 dims.
    int m_loc = tid >> 4, s = tid & 15, dd = s * 2;
    const float* urow = uf + (size_t)(b * M_ + m0 + m_loc) * 8;
    const float* w0 = Wu + (h * HD_ + dd) * 8;
    float x0 = 0.f, x1 = 0.f;
    #pragma unroll
    for (int i = 0; i < 8; ++i) { float u = urow[i]; x0 = fmaf(u, w0[i], x0); x1 = fmaf(u, w0[8 + i], x1); }
    float sm = x0 + x1;
    #pragma unroll
    for (int o = 8; o > 0; o >>= 1) sm += __shfl_xor(sm, o, 64);
    float mean = sm * (1.f / 32.f);
    float d0 = x0 - mean, d1 = x1 - mean;
    float vv = fmaf(d0, d0, d1 * d1);
    #pragma unroll
    for (int o = 8; o > 0; o >>= 1) vv += __shfl_xor(vv, o, 64);
    float rs = rsqrtf(vv * (1.f / 32.f) + 1e-5f);
    float y0 = fmaf(d0 * rs, gu[h * HD_ + dd],     bu[h * HD_ + dd]);
    float y1 = fmaf(d1 * rs, gu[h * HD_ + dd + 1], bu[h * HD_ + dd + 1]);
    rows[dd * 16 + m_loc]       = __half_as_ushort(__float2half(lrelu_f(y0)));
    rows[(dd + 1) * 16 + m_loc] = __half_as_ushort(__float2half(lrelu_f(y1)));
  }
  {  // A projection + in-thread LN + leaky -> As[d][n] f16 (transposed, conflict-free)
    float a0 = af[(b * N_ + n) * 2 + 0], a1 = af[(b * N_ + n) * 2 + 1];
    float ar[HD_]; float sm = 0.f;
    #pragma unroll
    for (int d = 0; d < HD_; ++d) {
      ar[d] = fmaf(a0, Wa[(h * HD_ + d) * 2], a1 * Wa[(h * HD_ + d) * 2 + 1]);
      sm += ar[d];
    }
    float mean = sm * (1.f / 32.f); float vv = 0.f;
    #pragma unroll
    for (int d = 0; d < HD_; ++d) { ar[d] -= mean; vv = fmaf(ar[d], ar[d], vv); }
    float rs = rsqrtf(vv * (1.f / 32.f) + 1e-5f);
    #pragma unroll
    for (int d = 0; d < HD_; ++d)
      As[d * N_ + n] = __half_as_ushort(__float2half(
          lrelu_f(fmaf(ar[d] * rs, ga[h * HD_ + d], ba[h * HD_ + d]))));
  }
  __syncthreads();
  float vw = vw_s;
  float tmf[MCH_];
  #pragma unroll
  for (int mm = 0; mm < MCH_; ++mm) {
    float e = edge[(size_t)(b * M_ + m0 + mm) * N_ + n];
    tmf[mm] = e * rsqrtf(fmaf(e * e, vw, 1e-5f));
  }
  __half2 tm2[4];
  #pragma unroll
  for (int j = 0; j < 4; ++j) tm2[j] = __floats2half2_rn(tmf[2 * j], tmf[2 * j + 1]);
  const __half2 hz = __float2half2_rn(0.f);
  const __half2 c06 = __float2half2_rn(0.6f), c04 = __float2half2_rn(0.4f);
  float scF[MCH_];
  #pragma unroll
  for (int mm = 0; mm < MCH_; ++mm) scF[mm] = 0.f;
  __half2 sc2[4] = {hz, hz, hz, hz};
  #pragma unroll
  for (int dc = 0; dc < 4; ++dc) {        // 4 chunks of 8 d, f32 flush per chunk
    #pragma unroll
    for (int dk = 0; dk < 8; ++dk) {
      int d = dc * 8 + dk;
      __half2 ad2 = __half2half2(__ushort_as_half(As[d * N_ + n]));
      uint4 ru = *(const uint4*)&rows[d * 16];       // 8 U f16 (4 m-pairs)
      uint4 rc = *(const uint4*)&rows[d * 16 + 8];   // cc, bb, vz, vw
      __half2 cc = u2h_(rc.x), bb = u2h_(rc.y), vz = u2h_(rc.z), vw2 = u2h_(rc.w);
      unsigned ruv[4] = {ru.x, ru.y, ru.z, ru.w};
      #pragma unroll
      for (int j = 0; j < 4; ++j) {
        __half2 w2 = __hfma2(tm2[j], cc, bb);
        __half2 adu = __hadd2(ad2, u2h_(ruv[j]));
        __half2 x2 = __hfma2(c06, w2, __hfma2(c04, habs2_(w2), adu));
        sc2[j] = __hfma2(vz, x2, __hfma2(vw2, habs2_(x2), sc2[j]));
      }
    }
    #pragma unroll
    for (int j = 0; j < 4; ++j) {
      float2 f = __half22float2(sc2[j]);
      scF[2 * j] += f.x; scF[2 * j + 1] += f.y;
      sc2[j] = hz;
    }
  }
  // batched softmax over n for all 8 m's: 2 barriers
  #pragma unroll
  for (int mm = 0; mm < MCH_; ++mm) {
    float v = scF[mm];
    #pragma unroll
    for (int o = 32; o > 0; o >>= 1) v = fmaxf(v, __shfl_xor(v, o, 64));
    if (lane == 0) wred[0][mm][wid] = v;
  }
  __syncthreads();
  #pragma unroll
  for (int mm = 0; mm < MCH_; ++mm) {
    float mx = fmaxf(fmaxf(wred[0][mm][0], wred[0][mm][1]),
                     fmaxf(wred[0][mm][2], wred[0][mm][3]));
    float em = __expf(scF[mm] - mx);
    scF[mm] = em;
    float ss = em;
    #pragma unroll
    for (int o = 32; o > 0; o >>= 1) ss += __shfl_xor(ss, o, 64);
    if (lane == 0) wred[1][mm][wid] = ss;
  }
  __syncthreads();
  #pragma unroll
  for (int mm = 0; mm < MCH_; ++mm) {
    float tot = (wred[1][mm][0] + wred[1][mm][1]) + (wred[1][mm][2] + wred[1][mm][3]);
    scF[mm] = scF[mm] / tot;
  }
  __half2 al2[4];
  #pragma unroll
  for (int j = 0; j < 4; ++j) al2[j] = __floats2half2_rn(scF[2 * j], scF[2 * j + 1]);
  // partial ant_out[n][d] = sum_m alpha_m U[m][d], packed pairs, f16 out
  #pragma unroll 8
  for (int d = 0; d < HD_; ++d) {
    uint4 ru = *(const uint4*)&rows[d * 16];
    unsigned ruv[4] = {ru.x, ru.y, ru.z, ru.w};
    __half2 pv = hz;
    #pragma unroll
    for (int j = 0; j < 4; ++j) pv = __hfma2(al2[j], u2h_(ruv[j]), pv);
    float2 pf = __half22float2(pv);
    accs[n * 34 + d] = __half_as_ushort(__float2half(pf.x + pf.y));
  }
  __syncthreads();
  // coalesced u32-pair sweep to P (f16, [n][d] layout)
  unsigned short* Pbase = P + (size_t)((mc * 4 + h) * B_ + b) * (N_ * HD_);
  #pragma unroll
  for (int k = 0; k < 16; ++k) {
    int i = tid + 256 * k;            // u32 index over 4096
    int nn = i >> 4, dp = i & 15;
    *(unsigned*)&Pbase[nn * 32 + dp * 2] = *(const unsigned*)&accs[nn * 34 + dp * 2];
  }
}

// ---------------- K3: sum f16 partials -> residual -> LN -> MLP (Wm1 in LDS) ---------
__global__ __launch_bounds__(256) void k3_mlp(
    const unsigned short* __restrict__ P, const float* __restrict__ af,
    const float* __restrict__ Wra, const float* __restrict__ bra,
    const float* __restrict__ gant, const float* __restrict__ bant,
    const float* __restrict__ Wm1, const float* __restrict__ bm1,
    const float* __restrict__ Wm2, const float* __restrict__ bm2,
    float* __restrict__ rd_in, float* __restrict__ rp_in)
{
  int b = blockIdx.x >> 4, nt = blockIdx.x & 15;
  int tid = threadIdx.x;
  int n_loc = tid >> 4, s = tid & 15;
  int n = nt * 16 + n_loc;
  int jj0 = s * 8;
  int hh = s >> 2, d0 = (s & 3) * 8;
  __shared__ float Wm1s[64][128];
  __shared__ float a2s[16][128];
  __shared__ float h1s[16][64];

  {  // stage Wm1 (32 KB) coalesced
    const float4* wg = (const float4*)Wm1;
    float4* wl = (float4*)Wm1s;
    #pragma unroll
    for (int k = 0; k < 8; ++k) wl[tid + 256 * k] = wg[tid + 256 * k];
  }
  float cat[8];
  #pragma unroll
  for (int k = 0; k < 8; ++k) cat[k] = 0.f;
  #pragma unroll
  for (int mc = 0; mc < MC_; ++mc) {
    const unsigned short* base = P + (size_t)((mc * 4 + hh) * B_ + b) * (N_ * HD_) + n * HD_ + d0;
    uint4 p = *(const uint4*)base;   // 8 f16
    float2 f;
    f = __half22float2(u2h_(p.x)); cat[0] += f.x; cat[1] += f.y;
    f = __half22float2(u2h_(p.y)); cat[2] += f.x; cat[3] += f.y;
    f = __half22float2(u2h_(p.z)); cat[4] += f.x; cat[5] += f.y;
    f = __half22float2(u2h_(p.w)); cat[6] += f.x; cat[7] += f.y;
  }
  float af0 = af[(b * N_ + n) * 2 + 0], af1 = af[(b * N_ + n) * 2 + 1];
  float a1[8]; float sm = 0.f;
  #pragma unroll
  for (int k = 0; k < 8; ++k) {
    int jj = jj0 + k;
    float r = fmaf(Wra[jj * 2], af0, fmaf(Wra[jj * 2 + 1], af1, bra[jj]));
    a1[k] = fmaxf(cat[k] + lrelu_f(r), 0.f);
    sm += a1[k];
  }
  #pragma unroll
  for (int o = 8; o > 0; o >>= 1) sm += __shfl_xor(sm, o, 64);
  float mean = sm * (1.f / 128.f);
  float vv = 0.f;
  #pragma unroll
  for (int k = 0; k < 8; ++k) { a1[k] -= mean; vv = fmaf(a1[k], a1[k], vv); }
  #pragma unroll
  for (int o = 8; o > 0; o >>= 1) vv += __shfl_xor(vv, o, 64);
  float rs = rsqrtf(vv * (1.f / 128.f) + 1e-5f);
  #pragma unroll
  for (int k = 0; k < 8; ++k) {
    int jj = jj0 + k;
    a2s[n_loc][jj] = fmaf(a1[k] * rs, gant[jj], bant[jj]);
  }
  __syncthreads();
  // h1 = relu(Wm1 @ a2 + bm1): rotated chunks (2-way max)
  #pragma unroll
  for (int k = 0; k < 4; ++k) {
    int o = tid + 256 * k;
    int row = o & 63, nl = o >> 6;
    const float4* wr = (const float4*)Wm1s[row];
    const float4* xr = (const float4*)a2s[nl];
    float c0 = 0.f, c1 = 0.f, c2 = 0.f, c3 = 0.f;
    #pragma unroll
    for (int c = 0; c < 32; ++c) {
      int cc = (c + row) & 31;
      float4 w = wr[cc], x = xr[cc];
      c0 = fmaf(w.x, x.x, c0); c1 = fmaf(w.y, x.y, c1);
      c2 = fmaf(w.z, x.z, c2); c3 = fmaf(w.w, x.w, c3);
    }
    h1s[nl][row] = fmaxf((c0 + c1) + (c2 + c3) + bm1[row], 0.f);
  }
  __syncthreads();
  {  // ant2d: 2 outputs per n; 8 threads per (n,c)
    int c = s >> 3, e0 = (s & 7) * 8;
    float p = 0.f;
    #pragma unroll
    for (int k = 0; k < 8; ++k) p = fmaf(h1s[n_loc][e0 + k], Wm2[c * 64 + e0 + k], p);
    #pragma unroll
    for (int o = 4; o > 0; o >>= 1) p += __shfl_xor(p, o, 64);
    if ((s & 7) == 0) {
      float v = p + bm2[c];
      v = fminf(fmaxf(v, 0.f), 200.f);
      (c == 0 ? rd_in : rp_in)[b * N_ + n] = v;
    }
  }
}

// ---------------- K4a: first readout layer, both paths; 1 wave per output row --------
__global__ __launch_bounds__(256) void k4a_l1(
    const float* __restrict__ rd_in, const float* __restrict__ rp_in,
    const float* __restrict__ Wd1, const float* __restrict__ bd1,
    const float* __restrict__ Wp1, const float* __restrict__ bp1,
    float* __restrict__ d1buf)
{
  int r = blockIdx.x * 4 + (threadIdx.x >> 6);
  int lane = threadIdx.x & 63;
  int path = r >> 13;
  int rem = r & 8191;
  int b = rem >> 9, i = rem & 511;
  const float* W = (path ? Wp1 : Wd1) + (size_t)i * N_;
  const float* bias = path ? bp1 : bd1;
  const float* x = (path ? rp_in : rd_in) + b * N_;
  float4 w = ((const float4*)W)[lane];
  float4 xv = ((const float4*)x)[lane];
  float s = fmaf(w.x, xv.x, fmaf(w.y, xv.y, fmaf(w.z, xv.z, w.w * xv.w)));
  #pragma unroll
  for (int o = 32; o > 0; o >>= 1) s += __shfl_xor(s, o, 64);
  if (lane == 0) d1buf[r] = fmaxf(s + bias[i], 0.f);
}

// ---------------- K4b: second readout layer --------------------------------------
__global__ __launch_bounds__(256) void k4b_l2(
    const float* __restrict__ d1buf,
    const float* __restrict__ Wd2, const float* __restrict__ bd2,
    const float* __restrict__ Wp2, const float* __restrict__ bp2,
    float* __restrict__ rdbuf, float* __restrict__ rpbuf)
{
  int r = blockIdx.x * 4 + (threadIdx.x >> 6);
  int lane = threadIdx.x & 63;
  int path = r >> 12;
  int rem = r & 4095;
  int b = rem >> 8, n = rem & 255;
  const float* W = (path ? Wp2 : Wd2) + (size_t)n * (2 * N_);
  const float* x = d1buf + path * (B_ * 2 * N_) + b * (2 * N_);
  float4 w0 = ((const float4*)W)[lane * 2], w1 = ((const float4*)W)[lane * 2 + 1];
  float4 x0 = ((const float4*)x)[lane * 2], x1 = ((const float4*)x)[lane * 2 + 1];
  float s = fmaf(w0.x, x0.x, fmaf(w0.y, x0.y, fmaf(w0.z, x0.z, w0.w * x0.w)));
  s = fmaf(w1.x, x1.x, fmaf(w1.y, x1.y, fmaf(w1.z, x1.z, fmaf(w1.w, x1.w, s))));
  #pragma unroll
  for (int o = 32; o > 0; o >>= 1) s += __shfl_xor(s, o, 64);
  if (lane == 0) {
    if (path == 0) {
      float rd = s + bd2[n];
      rd = fminf(fmaxf(rd, 0.f), 100.f);
      rdbuf[b * N_ + n] = rd;
    } else {
      float rp = s + bp2[n];
      if (isnan(rp)) rp = 0.f;
      else if (isinf(rp)) rp = rp > 0.f ? 1.f : 0.f;
      float pa = fminf(fmaxf(rp, 0.f), 1.f);
      rpbuf[b * N_ + n] = pa;
    }
  }
}

// ---------------- K4c: per-batch sums, cumsum, outputs 0, 2 and edge (out 1) ---------
__global__ __launch_bounds__(256) void k4c_final(
    const float* __restrict__ rdbuf, const float* __restrict__ rpbuf,
    const float* __restrict__ uf,
    float* __restrict__ out_af, float* __restrict__ out_pos, float* __restrict__ out_edge)
{
  int b = blockIdx.x >> 4, g = blockIdx.x & 15;
  int q = threadIdx.x;
  int lane = q & 63, wid = q >> 6;
  __shared__ float red[8];
  float rd = rdbuf[b * N_ + q];
  float pa = rpbuf[b * N_ + q];
  float s = rd, s2 = pa;
  #pragma unroll
  for (int o = 32; o > 0; o >>= 1) { s += __shfl_xor(s, o, 64); s2 += __shfl_xor(s2, o, 64); }
  if (lane == 0) { red[wid] = s; red[4 + wid] = s2; }
  __syncthreads();
  float sd = red[0] + red[1] + red[2] + red[3];
  float sp = red[4] + red[5] + red[6] + red[7];
  const float Bmax = 2.f * 2.0f - (N_ - 1) * 0.01f;   // 1.45
  float f = Bmax / fmaxf(Bmax, sd);
  float sdelta = fminf(fmaxf(f * rd, 0.f), 100.f);
  float sfp = 1.0f / fmaxf(sp, 1e-3f);                 // PMAX=1
  float spow = fminf(sfp * pa, 1.f);
  float val = sdelta;
  #pragma unroll
  for (int o = 1; o < 64; o <<= 1) {
    float t = __shfl_up(val, o, 64);
    if (lane >= o) val += t;
  }
  __syncthreads();
  if (lane == 63) red[wid] = val;
  __syncthreads();
  float off = 0.f;
  #pragma unroll
  for (int w2 = 0; w2 < 4; ++w2) if (w2 < wid) off += red[w2];
  float x = val + off + (float)q * 0.01f - (float)(q + 1) * 2.0f;
  if (g == 0) {
    out_af[(b * N_ + q) * 2 + 0] = sdelta;
    out_af[(b * N_ + q) * 2 + 1] = spow;
    out_pos[(b * N_ + q) * 3 + 0] = x;
    out_pos[(b * N_ + q) * 3 + 1] = 0.f;
    out_pos[(b * N_ + q) * 3 + 2] = 10.0f;
  }
  #pragma unroll
  for (int k = 0; k < 8; ++k) {
    int m = g * 8 + k;
    float u0 = uf[(b * M_ + m) * 8 + 0], u1 = uf[(b * M_ + m) * 8 + 1];
    float dx = u0 - x;
    out_edge[(size_t)(b * M_ + m) * N_ + q] = sqrtf(fmaf(dx, dx, u1 * u1));
  }
}

extern "C" void kernel_launch(void* const* d_in, const int* in_sizes, int n_in,
                              void* d_out, int out_size, void* d_ws, size_t ws_size,
                              hipStream_t stream) {
  (void)in_sizes; (void)n_in; (void)out_size; (void)ws_size;
  const float* uf   = (const float*)d_in[0];
  const float* af   = (const float*)d_in[1];
  const float* edge = (const float*)d_in[2];
  const float* Wu   = (const float*)d_in[3];
  const float* gu   = (const float*)d_in[4];
  const float* bu   = (const float*)d_in[5];
  const float* Wa   = (const float*)d_in[6];
  const float* ga   = (const float*)d_in[7];
  const float* ba   = (const float*)d_in[8];
  const float* We   = (const float*)d_in[9];
  const float* ge   = (const float*)d_in[10];
  const float* be   = (const float*)d_in[11];
  const float* av   = (const float*)d_in[12];
  const float* Wra  = (const float*)d_in[13];
  const float* bra  = (const float*)d_in[14];
  const float* gant = (const float*)d_in[15];
  const float* bant = (const float*)d_in[16];
  const float* Wm1  = (const float*)d_in[17];
  const float* bm1  = (const float*)d_in[18];
  const float* Wm2  = (const float*)d_in[19];
  const float* bm2  = (const float*)d_in[20];
  const float* Wd1  = (const float*)d_in[21];
  const float* bd1  = (const float*)d_in[22];
  const float* Wd2  = (const float*)d_in[23];
  const float* bd2  = (const float*)d_in[24];
  const float* Wp1  = (const float*)d_in[25];
  const float* bp1  = (const float*)d_in[26];
  const float* Wp2  = (const float*)d_in[27];
  const float* bp2  = (const float*)d_in[28];

  float* ws    = (float*)d_ws;
  unsigned short* P = (unsigned short*)d_ws;  // 8,388,608 f16 partials = 16 MB
  float* rd_in = ws + 4194304;       // 4096
  float* rp_in = ws + 4198400;       // 4096
  float* d1buf = ws + 4202496;       // 16384 (2 paths x 16 b x 512)
  float* rdbuf = ws + 4218880;       // 4096
  float* rpbuf = ws + 4222976;       // 4096

  float* out      = (float*)d_out;
  float* out_af   = out;             // [B,N,2]   = 8192
  float* out_edge = out + 8192;      // [B,M,N,1] = 524288
  float* out_pos  = out + 532480;    // [B,N,3]   = 12288

  hipLaunchKernelGGL(k2_attn, dim3(1024), dim3(256), 0, stream,
                     uf, af, edge, Wu, gu, bu, Wa, ga, ba, We, ge, be, av, P);
  hipLaunchKernelGGL(k3_mlp, dim3(256), dim3(256), 0, stream,
                     P, af, Wra, bra, gant, bant, Wm1, bm1, Wm2, bm2, rd_in, rp_in);
  hipLaunchKernelGGL(k4a_l1, dim3(4096), dim3(256), 0, stream,
                     rd_in, rp_in, Wd1, bd1, Wp1, bp1, d1buf);
  hipLaunchKernelGGL(k4b_l2, dim3(2048), dim3(256), 0, stream,
                     d1buf, Wd2, bd2, Wp2, bp2, rdbuf, rpbuf);
  hipLaunchKernelGGL(k4c_final, dim3(256), dim3(256), 0, stream,
                     rdbuf, rpbuf, uf, out_af, out_pos, out_edge);
}

// Round 9
// 164.586 us; speedup vs baseline: 1.1503x; 1.1503x over previous
//
#include <hip/hip_runtime.h>
#include <hip/hip_fp16.h>
#include <math.h>

#define H_   4
#define HD_  32
#define B_   16
#define M_   128
#define N_   256
#define MC_  16                      /* m-chunks (partials) */
#define MCH_ 8                       /* m's per chunk */
#define SCALE_ 0.17677669529663687f  /* 1/sqrt(32) */

__device__ __forceinline__ float lrelu_f(float x) { return x >= 0.f ? x : 0.2f * x; }

__device__ __forceinline__ __half2 u2h_(unsigned u) {
  union { unsigned u; __half2 h; } c; c.u = u; return c.h;
}
__device__ __forceinline__ unsigned h2u_(__half2 h) {
  union { __half2 h; unsigned u; } c; c.h = h; return c.u;
}

// ---------------- K2: proj(U,A)+LN fused + scores -> softmax -> partial ant_out ------
// Round-7 skeleton (f32 math, pad-33 A rows, 8 m/block, grid 1024). Width cuts only:
// U chunk in LDS as f16 (1 b128/d instead of 2), P partials stored f16.
__global__ __launch_bounds__(256) void k2_attn(
    const float* __restrict__ uf, const float* __restrict__ af,
    const float* __restrict__ edge,
    const float* __restrict__ Wu, const float* __restrict__ gu, const float* __restrict__ bu,
    const float* __restrict__ Wa, const float* __restrict__ ga, const float* __restrict__ ba,
    const float* __restrict__ We, const float* __restrict__ ge, const float* __restrict__ be,
    const float* __restrict__ av, unsigned short* __restrict__ P)
{
  int blk = blockIdx.x;
  int h = blk & 3, b = (blk >> 2) & 15, mc = blk >> 6;   // mc in 0..15
  int tid = threadIdx.x, n = tid;
  int lane = tid & 63, wid = tid >> 6;
  __shared__ float AB[N_ * 33];                 // A rows then acc rows, pad 33
  __shared__ __align__(16) unsigned short Uh[HD_][8];  // U chunk f16: [d][m], 16B/row
  __shared__ float4 cbv[HD_];                   // (c_d, b_d, 0.6*v*S, 0.4*v*S)
  __shared__ float wred[2][MCH_][4];
  __shared__ float vw_s;

  if (tid < 32) {                         // per-head edge-LN constants
    int d = tid;
    float w = We[h * HD_ + d];
    float s = w;
    #pragma unroll
    for (int o = 16; o > 0; o >>= 1) s += __shfl_xor(s, o, 32);
    float mw = s * (1.f / 32.f);
    float df = w - mw;
    float v2 = df * df;
    #pragma unroll
    for (int o = 16; o > 0; o >>= 1) v2 += __shfl_xor(v2, o, 32);
    if (d == 0) vw_s = v2 * (1.f / 32.f);
    float vv = av[h * HD_ + d] * SCALE_;
    cbv[d] = make_float4(df * ge[h * HD_ + d], be[h * HD_ + d], 0.6f * vv, 0.4f * vv);
  }
  int m0 = mc * MCH_;
  if (tid < 128) {  // U projection + LN + leaky -> Uh f16. 16 thr/row, 2 dims each.
    int m_loc = tid >> 4, s = tid & 15, dd = s * 2;
    const float* urow = uf + (size_t)(b * M_ + m0 + m_loc) * 8;
    const float* w0 = Wu + (h * HD_ + dd) * 8;
    float x0 = 0.f, x1 = 0.f;
    #pragma unroll
    for (int i = 0; i < 8; ++i) { float u = urow[i]; x0 = fmaf(u, w0[i], x0); x1 = fmaf(u, w0[8 + i], x1); }
    float sm = x0 + x1;
    #pragma unroll
    for (int o = 8; o > 0; o >>= 1) sm += __shfl_xor(sm, o, 64);
    float mean = sm * (1.f / 32.f);
    float d0 = x0 - mean, d1 = x1 - mean;
    float vv = fmaf(d0, d0, d1 * d1);
    #pragma unroll
    for (int o = 8; o > 0; o >>= 1) vv += __shfl_xor(vv, o, 64);
    float rs = rsqrtf(vv * (1.f / 32.f) + 1e-5f);
    float y0 = fmaf(d0 * rs, gu[h * HD_ + dd],     bu[h * HD_ + dd]);
    float y1 = fmaf(d1 * rs, gu[h * HD_ + dd + 1], bu[h * HD_ + dd + 1]);
    Uh[dd][m_loc]     = __half_as_ushort(__float2half(lrelu_f(y0)));
    Uh[dd + 1][m_loc] = __half_as_ushort(__float2half(lrelu_f(y1)));
  }
  {  // A projection + in-thread LN + leaky -> own AB row (short ar[] lifetime)
    float a0 = af[(b * N_ + n) * 2 + 0], a1 = af[(b * N_ + n) * 2 + 1];
    float ar[HD_]; float sm = 0.f;
    #pragma unroll
    for (int d = 0; d < HD_; ++d) {
      ar[d] = fmaf(a0, Wa[(h * HD_ + d) * 2], a1 * Wa[(h * HD_ + d) * 2 + 1]);
      sm += ar[d];
    }
    float mean = sm * (1.f / 32.f); float vv = 0.f;
    #pragma unroll
    for (int d = 0; d < HD_; ++d) { ar[d] -= mean; vv = fmaf(ar[d], ar[d], vv); }
    float rs = rsqrtf(vv * (1.f / 32.f) + 1e-5f);
    #pragma unroll
    for (int d = 0; d < HD_; ++d)
      AB[n * 33 + d] = lrelu_f(fmaf(ar[d] * rs, ga[h * HD_ + d], ba[h * HD_ + d]));
  }
  __syncthreads();
  float vw = vw_s;
  float tm[MCH_];
  #pragma unroll
  for (int mm = 0; mm < MCH_; ++mm) {
    float e = edge[(size_t)(b * M_ + m0 + mm) * N_ + n];
    tm[mm] = e * rsqrtf(fmaf(e * e, vw, 1e-5f));
  }
  float sc[MCH_];
  #pragma unroll
  for (int mm = 0; mm < MCH_; ++mm) sc[mm] = 0.f;
  const float* arow = &AB[n * 33];
  #pragma unroll 4
  for (int d = 0; d < HD_; ++d) {
    float ad = arow[d];
    float4 qc = cbv[d];
    uint4 up = *(const uint4*)&Uh[d][0];          // 8 U f16
    float2 u01 = __half22float2(u2h_(up.x));
    float2 u23 = __half22float2(u2h_(up.y));
    float2 u45 = __half22float2(u2h_(up.z));
    float2 u67 = __half22float2(u2h_(up.w));
#define STEP(mi, uval) { float w_ = fmaf(tm[mi], qc.x, qc.y); \
    float E_ = fmaf(0.4f, fabsf(w_), 0.6f * w_); \
    float x_ = ad + uval + E_; \
    sc[mi] = fmaf(qc.z, x_, fmaf(qc.w, fabsf(x_), sc[mi])); }
    STEP(0, u01.x)  STEP(1, u01.y)  STEP(2, u23.x)  STEP(3, u23.y)
    STEP(4, u45.x)  STEP(5, u45.y)  STEP(6, u67.x)  STEP(7, u67.y)
#undef STEP
  }
  // batched softmax over n for all 8 m's: 2 barriers total
  #pragma unroll
  for (int mm = 0; mm < MCH_; ++mm) {
    float v = sc[mm];
    #pragma unroll
    for (int o = 32; o > 0; o >>= 1) v = fmaxf(v, __shfl_xor(v, o, 64));
    if (lane == 0) wred[0][mm][wid] = v;
  }
  __syncthreads();
  #pragma unroll
  for (int mm = 0; mm < MCH_; ++mm) {
    float mx = fmaxf(fmaxf(wred[0][mm][0], wred[0][mm][1]),
                     fmaxf(wred[0][mm][2], wred[0][mm][3]));
    float em = __expf(sc[mm] - mx);
    sc[mm] = em;
    float ss = em;
    #pragma unroll
    for (int o = 32; o > 0; o >>= 1) ss += __shfl_xor(ss, o, 64);
    if (lane == 0) wred[1][mm][wid] = ss;
  }
  __syncthreads();
  #pragma unroll
  for (int mm = 0; mm < MCH_; ++mm) {
    float tot = (wred[1][mm][0] + wred[1][mm][1]) + (wred[1][mm][2] + wred[1][mm][3]);
    sc[mm] = sc[mm] / tot;
  }
  __syncthreads();                 // everyone done reading own A row before overwrite
  // partial ant_out[n][d] = sum_mm alpha[mm] * U[mm][d] into own AB row
  float* accr = &AB[n * 33];
  #pragma unroll 4
  for (int d = 0; d < HD_; ++d) {
    uint4 up = *(const uint4*)&Uh[d][0];
    float2 u01 = __half22float2(u2h_(up.x));
    float2 u23 = __half22float2(u2h_(up.y));
    float2 u45 = __half22float2(u2h_(up.z));
    float2 u67 = __half22float2(u2h_(up.w));
    float a0 = 0.f;
    a0 = fmaf(sc[0], u01.x, a0);  a0 = fmaf(sc[1], u01.y, a0);
    a0 = fmaf(sc[2], u23.x, a0);  a0 = fmaf(sc[3], u23.y, a0);
    a0 = fmaf(sc[4], u45.x, a0);  a0 = fmaf(sc[5], u45.y, a0);
    a0 = fmaf(sc[6], u67.x, a0);  a0 = fmaf(sc[7], u67.y, a0);
    accr[d] = a0;
  }
  __syncthreads();
  // coalesced sweep to P as f16 pairs (u32 stores)
  unsigned short* Pbase = P + (size_t)((mc * 4 + h) * B_ + b) * (N_ * HD_);
  #pragma unroll
  for (int k = 0; k < 16; ++k) {
    int i = tid + 256 * k;            // u32 index over 4096
    int nn = i >> 4, dp = (i & 15) * 2;
    __half2 hp = __floats2half2_rn(AB[nn * 33 + dp], AB[nn * 33 + dp + 1]);
    *(unsigned*)&Pbase[nn * 32 + dp] = h2u_(hp);
  }
}

// ---------------- K3: sum f16 partials -> residual -> LN -> MLP (Wm1 in LDS) ---------
__global__ __launch_bounds__(256) void k3_mlp(
    const unsigned short* __restrict__ P, const float* __restrict__ af,
    const float* __restrict__ Wra, const float* __restrict__ bra,
    const float* __restrict__ gant, const float* __restrict__ bant,
    const float* __restrict__ Wm1, const float* __restrict__ bm1,
    const float* __restrict__ Wm2, const float* __restrict__ bm2,
    float* __restrict__ rd_in, float* __restrict__ rp_in)
{
  int b = blockIdx.x >> 4, nt = blockIdx.x & 15;
  int tid = threadIdx.x;
  int n_loc = tid >> 4, s = tid & 15;
  int n = nt * 16 + n_loc;
  int jj0 = s * 8;
  int hh = s >> 2, d0 = (s & 3) * 8;
  __shared__ float Wm1s[64][128];
  __shared__ float a2s[16][128];
  __shared__ float h1s[16][64];

  {  // stage Wm1 (32 KB) coalesced
    const float4* wg = (const float4*)Wm1;
    float4* wl = (float4*)Wm1s;
    #pragma unroll
    for (int k = 0; k < 8; ++k) wl[tid + 256 * k] = wg[tid + 256 * k];
  }
  float cat[8];
  #pragma unroll
  for (int k = 0; k < 8; ++k) cat[k] = 0.f;
  #pragma unroll
  for (int mc = 0; mc < MC_; ++mc) {
    const unsigned short* base = P + (size_t)((mc * 4 + hh) * B_ + b) * (N_ * HD_) + n * HD_ + d0;
    uint4 p = *(const uint4*)base;   // 8 f16
    float2 f;
    f = __half22float2(u2h_(p.x)); cat[0] += f.x; cat[1] += f.y;
    f = __half22float2(u2h_(p.y)); cat[2] += f.x; cat[3] += f.y;
    f = __half22float2(u2h_(p.z)); cat[4] += f.x; cat[5] += f.y;
    f = __half22float2(u2h_(p.w)); cat[6] += f.x; cat[7] += f.y;
  }
  float af0 = af[(b * N_ + n) * 2 + 0], af1 = af[(b * N_ + n) * 2 + 1];
  float a1[8]; float sm = 0.f;
  #pragma unroll
  for (int k = 0; k < 8; ++k) {
    int jj = jj0 + k;
    float r = fmaf(Wra[jj * 2], af0, fmaf(Wra[jj * 2 + 1], af1, bra[jj]));
    a1[k] = fmaxf(cat[k] + lrelu_f(r), 0.f);
    sm += a1[k];
  }
  #pragma unroll
  for (int o = 8; o > 0; o >>= 1) sm += __shfl_xor(sm, o, 64);
  float mean = sm * (1.f / 128.f);
  float vv = 0.f;
  #pragma unroll
  for (int k = 0; k < 8; ++k) { a1[k] -= mean; vv = fmaf(a1[k], a1[k], vv); }
  #pragma unroll
  for (int o = 8; o > 0; o >>= 1) vv += __shfl_xor(vv, o, 64);
  float rs = rsqrtf(vv * (1.f / 128.f) + 1e-5f);
  #pragma unroll
  for (int k = 0; k < 8; ++k) {
    int jj = jj0 + k;
    a2s[n_loc][jj] = fmaf(a1[k] * rs, gant[jj], bant[jj]);
  }
  __syncthreads();
  // h1 = relu(Wm1 @ a2 + bm1): rotated chunks (2-way max)
  #pragma unroll
  for (int k = 0; k < 4; ++k) {
    int o = tid + 256 * k;
    int row = o & 63, nl = o >> 6;
    const float4* wr = (const float4*)Wm1s[row];
    const float4* xr = (const float4*)a2s[nl];
    float c0 = 0.f, c1 = 0.f, c2 = 0.f, c3 = 0.f;
    #pragma unroll
    for (int c = 0; c < 32; ++c) {
      int cc = (c + row) & 31;
      float4 w = wr[cc], x = xr[cc];
      c0 = fmaf(w.x, x.x, c0); c1 = fmaf(w.y, x.y, c1);
      c2 = fmaf(w.z, x.z, c2); c3 = fmaf(w.w, x.w, c3);
    }
    h1s[nl][row] = fmaxf((c0 + c1) + (c2 + c3) + bm1[row], 0.f);
  }
  __syncthreads();
  {  // ant2d: 2 outputs per n; 8 threads per (n,c)
    int c = s >> 3, e0 = (s & 7) * 8;
    float p = 0.f;
    #pragma unroll
    for (int k = 0; k < 8; ++k) p = fmaf(h1s[n_loc][e0 + k], Wm2[c * 64 + e0 + k], p);
    #pragma unroll
    for (int o = 4; o > 0; o >>= 1) p += __shfl_xor(p, o, 64);
    if ((s & 7) == 0) {
      float v = p + bm2[c];
      v = fminf(fmaxf(v, 0.f), 200.f);
      (c == 0 ? rd_in : rp_in)[b * N_ + n] = v;
    }
  }
}

// ---------------- K4a: first readout layer, both paths; 1 wave per output row --------
__global__ __launch_bounds__(256) void k4a_l1(
    const float* __restrict__ rd_in, const float* __restrict__ rp_in,
    const float* __restrict__ Wd1, const float* __restrict__ bd1,
    const float* __restrict__ Wp1, const float* __restrict__ bp1,
    float* __restrict__ d1buf)
{
  int r = blockIdx.x * 4 + (threadIdx.x >> 6);
  int lane = threadIdx.x & 63;
  int path = r >> 13;
  int rem = r & 8191;
  int b = rem >> 9, i = rem & 511;
  const float* W = (path ? Wp1 : Wd1) + (size_t)i * N_;
  const float* bias = path ? bp1 : bd1;
  const float* x = (path ? rp_in : rd_in) + b * N_;
  float4 w = ((const float4*)W)[lane];
  float4 xv = ((const float4*)x)[lane];
  float s = fmaf(w.x, xv.x, fmaf(w.y, xv.y, fmaf(w.z, xv.z, w.w * xv.w)));
  #pragma unroll
  for (int o = 32; o > 0; o >>= 1) s += __shfl_xor(s, o, 64);
  if (lane == 0) d1buf[r] = fmaxf(s + bias[i], 0.f);
}

// ---------------- K4b: second readout layer --------------------------------------
__global__ __launch_bounds__(256) void k4b_l2(
    const float* __restrict__ d1buf,
    const float* __restrict__ Wd2, const float* __restrict__ bd2,
    const float* __restrict__ Wp2, const float* __restrict__ bp2,
    float* __restrict__ rdbuf, float* __restrict__ rpbuf)
{
  int r = blockIdx.x * 4 + (threadIdx.x >> 6);
  int lane = threadIdx.x & 63;
  int path = r >> 12;
  int rem = r & 4095;
  int b = rem >> 8, n = rem & 255;
  const float* W = (path ? Wp2 : Wd2) + (size_t)n * (2 * N_);
  const float* x = d1buf + path * (B_ * 2 * N_) + b * (2 * N_);
  float4 w0 = ((const float4*)W)[lane * 2], w1 = ((const float4*)W)[lane * 2 + 1];
  float4 x0 = ((const float4*)x)[lane * 2], x1 = ((const float4*)x)[lane * 2 + 1];
  float s = fmaf(w0.x, x0.x, fmaf(w0.y, x0.y, fmaf(w0.z, x0.z, w0.w * x0.w)));
  s = fmaf(w1.x, x1.x, fmaf(w1.y, x1.y, fmaf(w1.z, x1.z, fmaf(w1.w, x1.w, s))));
  #pragma unroll
  for (int o = 32; o > 0; o >>= 1) s += __shfl_xor(s, o, 64);
  if (lane == 0) {
    if (path == 0) {
      float rd = s + bd2[n];
      rd = fminf(fmaxf(rd, 0.f), 100.f);
      rdbuf[b * N_ + n] = rd;
    } else {
      float rp = s + bp2[n];
      if (isnan(rp)) rp = 0.f;
      else if (isinf(rp)) rp = rp > 0.f ? 1.f : 0.f;
      float pa = fminf(fmaxf(rp, 0.f), 1.f);
      rpbuf[b * N_ + n] = pa;
    }
  }
}

// ---------------- K4c: per-batch sums, cumsum, outputs 0, 2 and edge (out 1) ---------
__global__ __launch_bounds__(256) void k4c_final(
    const float* __restrict__ rdbuf, const float* __restrict__ rpbuf,
    const float* __restrict__ uf,
    float* __restrict__ out_af, float* __restrict__ out_pos, float* __restrict__ out_edge)
{
  int b = blockIdx.x >> 4, g = blockIdx.x & 15;
  int q = threadIdx.x;
  int lane = q & 63, wid = q >> 6;
  __shared__ float red[8];
  float rd = rdbuf[b * N_ + q];
  float pa = rpbuf[b * N_ + q];
  float s = rd, s2 = pa;
  #pragma unroll
  for (int o = 32; o > 0; o >>= 1) { s += __shfl_xor(s, o, 64); s2 += __shfl_xor(s2, o, 64); }
  if (lane == 0) { red[wid] = s; red[4 + wid] = s2; }
  __syncthreads();
  float sd = red[0] + red[1] + red[2] + red[3];
  float sp = red[4] + red[5] + red[6] + red[7];
  const float Bmax = 2.f * 2.0f - (N_ - 1) * 0.01f;   // 1.45
  float f = Bmax / fmaxf(Bmax, sd);
  float sdelta = fminf(fmaxf(f * rd, 0.f), 100.f);
  float sfp = 1.0f / fmaxf(sp, 1e-3f);                 // PMAX=1
  float spow = fminf(sfp * pa, 1.f);
  float val = sdelta;
  #pragma unroll
  for (int o = 1; o < 64; o <<= 1) {
    float t = __shfl_up(val, o, 64);
    if (lane >= o) val += t;
  }
  __syncthreads();
  if (lane == 63) red[wid] = val;
  __syncthreads();
  float off = 0.f;
  #pragma unroll
  for (int w2 = 0; w2 < 4; ++w2) if (w2 < wid) off += red[w2];
  float x = val + off + (float)q * 0.01f - (float)(q + 1) * 2.0f;
  if (g == 0) {
    out_af[(b * N_ + q) * 2 + 0] = sdelta;
    out_af[(b * N_ + q) * 2 + 1] = spow;
    out_pos[(b * N_ + q) * 3 + 0] = x;
    out_pos[(b * N_ + q) * 3 + 1] = 0.f;
    out_pos[(b * N_ + q) * 3 + 2] = 10.0f;
  }
  #pragma unroll
  for (int k = 0; k < 8; ++k) {
    int m = g * 8 + k;
    float u0 = uf[(b * M_ + m) * 8 + 0], u1 = uf[(b * M_ + m) * 8 + 1];
    float dx = u0 - x;
    out_edge[(size_t)(b * M_ + m) * N_ + q] = sqrtf(fmaf(dx, dx, u1 * u1));
  }
}

extern "C" void kernel_launch(void* const* d_in, const int* in_sizes, int n_in,
                              void* d_out, int out_size, void* d_ws, size_t ws_size,
                              hipStream_t stream) {
  (void)in_sizes; (void)n_in; (void)out_size; (void)ws_size;
  const float* uf   = (const float*)d_in[0];
  const float* af   = (const float*)d_in[1];
  const float* edge = (const float*)d_in[2];
  const float* Wu   = (const float*)d_in[3];
  const float* gu   = (const float*)d_in[4];
  const float* bu   = (const float*)d_in[5];
  const float* Wa   = (const float*)d_in[6];
  const float* ga   = (const float*)d_in[7];
  const float* ba   = (const float*)d_in[8];
  const float* We   = (const float*)d_in[9];
  const float* ge   = (const float*)d_in[10];
  const float* be   = (const float*)d_in[11];
  const float* av   = (const float*)d_in[12];
  const float* Wra  = (const float*)d_in[13];
  const float* bra  = (const float*)d_in[14];
  const float* gant = (const float*)d_in[15];
  const float* bant = (const float*)d_in[16];
  const float* Wm1  = (const float*)d_in[17];
  const float* bm1  = (const float*)d_in[18];
  const float* Wm2  = (const float*)d_in[19];
  const float* bm2  = (const float*)d_in[20];
  const float* Wd1  = (const float*)d_in[21];
  const float* bd1  = (const float*)d_in[22];
  const float* Wd2  = (const float*)d_in[23];
  const float* bd2  = (const float*)d_in[24];
  const float* Wp1  = (const float*)d_in[25];
  const float* bp1  = (const float*)d_in[26];
  const float* Wp2  = (const float*)d_in[27];
  const float* bp2  = (const float*)d_in[28];

  float* ws    = (float*)d_ws;
  unsigned short* P = (unsigned short*)d_ws;  // 8,388,608 f16 partials = 16 MB
  float* rd_in = ws + 4194304;       // 4096
  float* rp_in = ws + 4198400;       // 4096
  float* d1buf = ws + 4202496;       // 16384 (2 paths x 16 b x 512)
  float* rdbuf = ws + 4218880;       // 4096
  float* rpbuf = ws + 4222976;       // 4096

  float* out      = (float*)d_out;
  float* out_af   = out;             // [B,N,2]   = 8192
  float* out_edge = out + 8192;      // [B,M,N,1] = 524288
  float* out_pos  = out + 532480;    // [B,N,3]   = 12288

  hipLaunchKernelGGL(k2_attn, dim3(1024), dim3(256), 0, stream,
                     uf, af, edge, Wu, gu, bu, Wa, ga, ba, We, ge, be, av, P);
  hipLaunchKernelGGL(k3_mlp, dim3(256), dim3(256), 0, stream,
                     P, af, Wra, bra, gant, bant, Wm1, bm1, Wm2, bm2, rd_in, rp_in);
  hipLaunchKernelGGL(k4a_l1, dim3(4096), dim3(256), 0, stream,
                     rd_in, rp_in, Wd1, bd1, Wp1, bp1, d1buf);
  hipLaunchKernelGGL(k4b_l2, dim3(2048), dim3(256), 0, stream,
                     d1buf, Wd2, bd2, Wp2, bp2, rdbuf, rpbuf);
  hipLaunchKernelGGL(k4c_final, dim3(256), dim3(256), 0, stream,
                     rdbuf, rpbuf, uf, out_af, out_pos, out_edge);
}